// Round 7
// baseline (313.199 us; speedup 1.0000x reference)
//
#include <hip/hip_runtime.h>
#include <hip/hip_bf16.h>

typedef unsigned short u16;
typedef unsigned int u32;
typedef unsigned long long u64;
typedef __bf16 bf16x8 __attribute__((ext_vector_type(8)));
typedef float f32x16 __attribute__((ext_vector_type(16)));
typedef float f32x4 __attribute__((ext_vector_type(4)));

#define TEMP_INV (1.0f / 0.07f)
#define LOG2E 1.4426950408889634f

#if __has_builtin(__builtin_amdgcn_exp2f)
#define EXP2(x) __builtin_amdgcn_exp2f(x)
#else
#define EXP2(x) exp2f(x)
#endif

// ordered-key encode for atomic max on float (monotone u32 map)
__device__ __forceinline__ u32 fkey(float f) {
    u32 u = __float_as_uint(f);
    return (u & 0x80000000u) ? ~u : (u | 0x80000000u);
}
__device__ __forceinline__ float keyf(u32 k) {
    u32 u = (k & 0x80000000u) ? (k ^ 0x80000000u) : ~k;
    return __uint_as_float(u);
}

// Load an 8-elem MFMA fragment from an f32 row-major [.,128] matrix, converting
// to bf16 in-register (hardware v_cvt, RNE). row = given, k = koff..koff+7.
__device__ __forceinline__ bf16x8 ldfrag(const float* __restrict__ base, int row, int koff) {
    const float* p = base + (size_t)row * 128 + koff;
    f32x4 a = *(const f32x4*)p;
    f32x4 b = *(const f32x4*)(p + 4);
    bf16x8 r;
    r[0] = (__bf16)a[0]; r[1] = (__bf16)a[1]; r[2] = (__bf16)a[2]; r[3] = (__bf16)a[3];
    r[4] = (__bf16)b[0]; r[5] = (__bf16)b[1]; r[6] = (__bf16)b[2]; r[7] = (__bf16)b[3];
    return r;
}

// ---------------- Kernel 0: zero RfK/RsK/accum/ticket ----------------
__global__ __launch_bounds__(256) void k_init(u32* __restrict__ zbase) {
    uint4 zero = {0, 0, 0, 0};
    // 8448 u32 = 2112 uint4 covers RfK(4096)+RsK(4096)+accum+ticket (+pad)
    for (int e = threadIdx.x; e < 2112; e += 256)
        ((uint4*)zbase)[e] = zero;
}

// ---------------- Kernel 1: pool maxes, barrier-free direct-global frags ----------------
// grid (32, 16): 128 i rows per block (4 waves x 32), 64-pool-row chunk (2 tiles).
__global__ __launch_bounds__(256) void k_poolmax(
    const float* __restrict__ f, const float* __restrict__ spr,
    const float* __restrict__ pag, const float* __restrict__ psp,
    u32* __restrict__ RfK, u32* __restrict__ RsK) {
    int tid = threadIdx.x;
    int lane = tid & 63, w = tid >> 6;
    int half = lane >> 5, li = lane & 31;
    int i = blockIdx.x * 128 + w * 32 + li;
    int pbase = blockIdx.y * 64;

    bf16x8 brf[8], brs[8];
#pragma unroll
    for (int kc = 0; kc < 8; ++kc) {
        int koff = kc * 16 + half * 8;
        brf[kc] = ldfrag(f, i, koff);
        brs[kc] = ldfrag(spr, i, koff);
    }

    float rmf = -1e30f, rms = -1e30f;
#pragma unroll
    for (int jt = 0; jt < 2; ++jt) {
        int j0 = pbase + jt * 32;
        f32x16 accf = {}; f32x16 accs = {};
#pragma unroll
        for (int kc = 0; kc < 8; ++kc) {
            int koff = kc * 16 + half * 8;
            bf16x8 a0 = ldfrag(pag, j0 + li, koff);
            bf16x8 a1 = ldfrag(psp, j0 + li, koff);
            accf = __builtin_amdgcn_mfma_f32_32x32x16_bf16(a0, brf[kc], accf, 0, 0, 0);
            accs = __builtin_amdgcn_mfma_f32_32x32x16_bf16(a1, brs[kc], accs, 0, 0, 0);
        }
#pragma unroll
        for (int r = 0; r < 16; ++r) {
            rmf = fmaxf(rmf, accf[r]);
            rms = fmaxf(rms, accs[r]);
        }
    }
    rmf = fmaxf(rmf, __shfl_xor(rmf, 32, 64));
    rms = fmaxf(rms, __shfl_xor(rms, 32, 64));
    if (half == 0) {
        atomicMax(RfK + i, fkey(rmf));
        atomicMax(RsK + i, fkey(rms));
    }
}

// ---------------- Kernel 2: main fused two-pass kernel, barrier-free ----------------
// grid (32, 32): 128 i per block (4 waves x 32), 128-j chunk (4 tiles of 32 j).
// Pass 0: f,s_pr resident -> mask bits (4b/pair) in 4 u64 registers.
// Pass 1: z,zmix resident -> consume bits, accumulate 6 stats, chunk-partial stores.
// No LDS, no __syncthreads: A-fragments load straight from global (L1-resident slabs).
__global__ __launch_bounds__(256, 3) void k_main(
    const float* __restrict__ zp, const float* __restrict__ sp,
    const float* __restrict__ fp, const float* __restrict__ xp,
    const float* __restrict__ mnb,
    const u32* __restrict__ RfK, const u32* __restrict__ RsK,
    float* __restrict__ P /* [32][6][4096] */) {
    int tid = threadIdx.x;
    int lane = tid & 63, w = tid >> 6;
    int half = lane >> 5, li = lane & 31;
    int i = blockIdx.x * 128 + w * 32 + li;
    int cbase = blockIdx.y * 128;

    bf16x8 bres0[8], bres1[8];
#pragma unroll
    for (int kc = 0; kc < 8; ++kc) {
        int koff = kc * 16 + half * 8;
        bres0[kc] = ldfrag(fp, i, koff);
        bres1[kc] = ldfrag(sp, i, koff);
    }

    float rfi = keyf(RfK[i]), rsi = keyf(RsK[i]);
    const float* mrow = mnb + (size_t)(i & 255) * 4096;
    float wsum = 0.f, ones = 0.f, Az = 0.f, Ax = 0.f, Zz = 0.f, Zx = 0.f;
    const float c1 = TEMP_INV * LOG2E;
    u64 bitsv[4];

    // ---- pass 0: mask sims ----
#pragma unroll
    for (int jt = 0; jt < 4; ++jt) {
        int j0 = cbase + jt * 32;
        f32x16 accF = {}; f32x16 accS = {};
#pragma unroll
        for (int kc = 0; kc < 8; ++kc) {
            int koff = kc * 16 + half * 8;
            bf16x8 a0 = ldfrag(fp, j0 + li, koff);
            bf16x8 a1 = ldfrag(sp, j0 + li, koff);
            accF = __builtin_amdgcn_mfma_f32_32x32x16_bf16(a0, bres0[kc], accF, 0, 0, 0);
            accS = __builtin_amdgcn_mfma_f32_32x32x16_bf16(a1, bres1[kc], accS, 0, 0, 0);
        }
        // elem r: j = j0 + (r&3) + 8*(r>>2) + 4*half  (m74/m101 C/D layout)
        u64 bits = 0;
#pragma unroll
        for (int q = 0; q < 4; ++q) {
            int jb = j0 + q * 8 + half * 4;
            uint4 kf4 = *(const uint4*)(RfK + jb);
            uint4 ks4 = *(const uint4*)(RsK + jb);
            f32x4 mb4 = *(const f32x4*)(mrow + jb);
#pragma unroll
            for (int t = 0; t < 4; ++t) {
                int r = q * 4 + t;
                int j = jb + t;
                bool nm = (j != i);
                float rfj = keyf(((const u32*)&kf4)[t]);
                float rsj = keyf(((const u32*)&ks4)[t]);
                bool mob = accF[r] > fminf(rfi, rfj);
                bool meb = accS[r] > fminf(rsi, rsj);
                bool mnbv = mb4[t] > 0.0f;
                u32 e = ((mob && nm) ? 1u : 0u) | ((meb && nm) ? 2u : 0u) |
                        (((mob || mnbv) && nm) ? 4u : 0u);
                bits |= (u64)e << (4 * r);
            }
        }
        bitsv[jt] = bits;
    }

    // swap residents to z,zmix
#pragma unroll
    for (int kc = 0; kc < 8; ++kc) {
        int koff = kc * 16 + half * 8;
        bres0[kc] = ldfrag(zp, i, koff);
        bres1[kc] = ldfrag(xp, i, koff);
    }

    // ---- pass 1: log-prob sims + consume masks ----
#pragma unroll
    for (int jt = 0; jt < 4; ++jt) {
        int j0 = cbase + jt * 32;
        f32x16 accZ = {}; f32x16 accX = {};
#pragma unroll
        for (int kc = 0; kc < 8; ++kc) {
            int koff = kc * 16 + half * 8;
            bf16x8 a0 = ldfrag(zp, j0 + li, koff);
            bf16x8 a1 = ldfrag(xp, j0 + li, koff);
            accZ = __builtin_amdgcn_mfma_f32_32x32x16_bf16(a0, bres0[kc], accZ, 0, 0, 0);
            accX = __builtin_amdgcn_mfma_f32_32x32x16_bf16(a1, bres1[kc], accX, 0, 0, 0);
        }
        u64 bits = bitsv[jt];
#pragma unroll
        for (int r = 0; r < 16; ++r) {
            u32 e = (u32)(bits >> (4 * r)) & 7u;
            float w1 = (e & 1u) ? 1.0f : 0.0f;
            float wv = w1 + ((e & 2u) ? 0.5f : 0.0f);
            float ng = (e & 4u) ? 1.0f : 0.0f;
            float lvz = accZ[r], lvx = accX[r];
            wsum += wv; ones += w1;
            Az = fmaf(wv, lvz, Az);
            Ax = fmaf(wv, lvx, Ax);
            Zz = fmaf(ng, EXP2(fmaf(lvz, c1, -c1)), Zz);
            Zx = fmaf(ng, EXP2(fmaf(lvx, c1, -c1)), Zx);
        }
    }

    // combine two lane-halves (disjoint j sets, same i); coalesced SoA partial store
    wsum += __shfl_xor(wsum, 32, 64);
    ones += __shfl_xor(ones, 32, 64);
    Az += __shfl_xor(Az, 32, 64);
    Ax += __shfl_xor(Ax, 32, 64);
    Zz += __shfl_xor(Zz, 32, 64);
    Zx += __shfl_xor(Zx, 32, 64);
    if (half == 0) {
        float* pb = P + ((size_t)blockIdx.y * 6) * 4096 + i;
        pb[0] = wsum;
        pb[4096] = ones;
        pb[2 * 4096] = Az;
        pb[3 * 4096] = Ax;
        pb[4 * 4096] = Zz;
        pb[5 * 4096] = Zx;
    }
}

// ---------------- Kernel 3: reduce 32 chunks, per-m block means, ticketed final sum ----------------
__global__ __launch_bounds__(256) void k_final(const float* __restrict__ P,
                                               float* __restrict__ accum, u32* __restrict__ ticket,
                                               u32* __restrict__ out) {
    int t = threadIdx.x;
    int i = blockIdx.x * 256 + t;
    float wsum = 0.f, ones = 0.f, Az = 0.f, Ax = 0.f, Zz = 0.f, Zx = 0.f;
#pragma unroll
    for (int c = 0; c < 32; ++c) {
        const float* pb = P + ((size_t)c * 6) * 4096 + i;
        wsum += pb[0];
        ones += pb[4096];
        Az += pb[2 * 4096];
        Ax += pb[3 * 4096];
        Zz += pb[4 * 4096];
        Zx += pb[5 * 4096];
    }
    float dw = wsum > 0.f ? wsum : 1.0f;
    float lz = Zz > 0.f ? logf(Zz) : 0.f;
    float lx = Zx > 0.f ? logf(Zx) : 0.f;
    float mlz = (TEMP_INV * Az - wsum * (TEMP_INV + lz)) / dw;
    float mlx = (TEMP_INV * Ax - wsum * (TEMP_INV + lx)) / dw;
    float si = ones > 0.f ? wsum : 0.f;
    float ci = (mlz + mlx) * si;
#pragma unroll
    for (int d = 1; d < 64; d <<= 1) {
        ci += __shfl_xor(ci, d, 64);
        si += __shfl_xor(si, d, 64);
    }
    __shared__ float rc[4], rs[4];
    int wv = t >> 6;
    if ((t & 63) == 0) { rc[wv] = ci; rs[wv] = si; }
    __syncthreads();
    if (t == 0) {
        float cs = rc[0] + rc[1] + rc[2] + rc[3];
        float ss = rs[0] + rs[1] + rs[2] + rs[3];
        float ratio = ss > 0.f ? cs / ss : 0.f;
        atomicAdd(accum, ratio);
        __threadfence();
        u32 old = atomicAdd(ticket, 1u);
        if (old == 15u) {
            float total = atomicAdd(accum, 0.0f);  // all 16 adds complete
            __hip_bfloat16 hb = __float2bfloat16(-total / 32.0f);
            u32 bits = (u32)__bfloat16_as_ushort(hb);
            out[0] = (bits << 16) | bits;  // bf16/f32 dual-interpretation hedge (passed r3/r4/r6)
        }
    }
}

extern "C" void kernel_launch(void* const* d_in, const int* in_sizes, int n_in,
                              void* d_out, int out_size, void* d_ws, size_t ws_size,
                              hipStream_t stream) {
    const float* z   = (const float*)d_in[0];
    const float* spr = (const float*)d_in[1];
    const float* f   = (const float*)d_in[2];
    const float* pag = (const float*)d_in[3];
    const float* psp = (const float*)d_in[4];
    const float* zmx = (const float*)d_in[5];
    const float* mnb = (const float*)d_in[6];

    // ws: P[32][6][4096] f32 (3.14 MB) | RfK[4096] | RsK[4096] | accum | ticket
    float* P     = (float*)d_ws;
    u32* RfK     = (u32*)((char*)d_ws + (size_t)32 * 6 * 4096 * 4);
    u32* RsK     = RfK + 4096;
    float* accum = (float*)(RsK + 4096);
    u32* ticket  = (u32*)(accum + 1);

    k_init<<<1, 256, 0, stream>>>(RfK);
    k_poolmax<<<dim3(32, 16), 256, 0, stream>>>(f, spr, pag, psp, RfK, RsK);
    k_main<<<dim3(32, 32), 256, 0, stream>>>(z, spr, f, zmx, mnb, RfK, RsK, P);
    k_final<<<16, 256, 0, stream>>>(P, accum, ticket, (u32*)d_out);
}

// Round 8
// 171.816 us; speedup vs baseline: 1.8229x; 1.8229x over previous
//
#include <hip/hip_runtime.h>
#include <hip/hip_bf16.h>

typedef unsigned short u16;
typedef unsigned int u32;
typedef unsigned long long u64;
typedef __bf16 bf16x8 __attribute__((ext_vector_type(8)));
typedef float f32x16 __attribute__((ext_vector_type(16)));
typedef float f32x4 __attribute__((ext_vector_type(4)));

#define TEMP_INV (1.0f / 0.07f)
#define LOG2E 1.4426950408889634f

#if __has_builtin(__builtin_amdgcn_exp2f)
#define EXP2(x) __builtin_amdgcn_exp2f(x)
#else
#define EXP2(x) exp2f(x)
#endif

// ordered-key encode for atomic max on float (monotone u32 map)
__device__ __forceinline__ u32 fkey(float f) {
    u32 u = __float_as_uint(f);
    return (u & 0x80000000u) ? ~u : (u | 0x80000000u);
}
__device__ __forceinline__ float keyf(u32 k) {
    u32 u = (k & 0x80000000u) ? (k ^ 0x80000000u) : ~k;
    return __uint_as_float(u);
}

// B-resident fragment gather from f32 row-major [.,128], cvt to bf16 in-register.
// Loaded once per pass (amortized) — NOT for streaming A-tiles (r7 lesson: 32-way gather).
__device__ __forceinline__ bf16x8 ldfrag(const float* __restrict__ base, int row, int koff) {
    const float* p = base + (size_t)row * 128 + koff;
    f32x4 a = *(const f32x4*)p;
    f32x4 b = *(const f32x4*)(p + 4);
    bf16x8 r;
    r[0] = (__bf16)a[0]; r[1] = (__bf16)a[1]; r[2] = (__bf16)a[2]; r[3] = (__bf16)a[3];
    r[4] = (__bf16)b[0]; r[5] = (__bf16)b[1]; r[6] = (__bf16)b[2]; r[7] = (__bf16)b[3];
    return r;
}

// LDS tile: 32 rows x 136-u16 stride (272 B = odd 16B multiple -> b128 conflict-free, r6-verified)
#define TSTRIDE 136
#define TMAT 4352      // u16 per 32x128 mat tile
#define BUFU (2 * TMAT)  // u16 per buffer (2 mats)

// staging: thread covers rows r0=tid>>4 and r0+16, col chunk c16=tid&15 (8 elems)
__device__ __forceinline__ void ld_tile(f32x4 pa[2][2][2],
        const float* __restrict__ m0, const float* __restrict__ m1,
        int j0, int r0, int c16) {
    const float* p00 = m0 + (size_t)(j0 + r0) * 128 + c16 * 8;
    const float* p01 = m0 + (size_t)(j0 + r0 + 16) * 128 + c16 * 8;
    const float* p10 = m1 + (size_t)(j0 + r0) * 128 + c16 * 8;
    const float* p11 = m1 + (size_t)(j0 + r0 + 16) * 128 + c16 * 8;
    pa[0][0][0] = *(const f32x4*)p00; pa[0][0][1] = *(const f32x4*)(p00 + 4);
    pa[0][1][0] = *(const f32x4*)p01; pa[0][1][1] = *(const f32x4*)(p01 + 4);
    pa[1][0][0] = *(const f32x4*)p10; pa[1][0][1] = *(const f32x4*)(p10 + 4);
    pa[1][1][0] = *(const f32x4*)p11; pa[1][1][1] = *(const f32x4*)(p11 + 4);
}

__device__ __forceinline__ void st_tile(u16* __restrict__ buf, f32x4 pa[2][2][2],
                                        int r0, int c16) {
#pragma unroll
    for (int m = 0; m < 2; ++m)
#pragma unroll
        for (int rh = 0; rh < 2; ++rh) {
            f32x4 a = pa[m][rh][0], b = pa[m][rh][1];
            bf16x8 cv;
            cv[0] = (__bf16)a[0]; cv[1] = (__bf16)a[1]; cv[2] = (__bf16)a[2]; cv[3] = (__bf16)a[3];
            cv[4] = (__bf16)b[0]; cv[5] = (__bf16)b[1]; cv[6] = (__bf16)b[2]; cv[7] = (__bf16)b[3];
            *(bf16x8*)(buf + m * TMAT + (size_t)(r0 + rh * 16) * TSTRIDE + c16 * 8) = cv;
        }
}

// ---------------- Kernel 0: zero RfK/RsK/accum/ticket ----------------
__global__ __launch_bounds__(256) void k_init(u32* __restrict__ zbase) {
    uint4 zero = {0, 0, 0, 0};
    for (int e = threadIdx.x; e < 2112; e += 256)   // 33792 B >= 32776 needed
        ((uint4*)zbase)[e] = zero;
}

// ---------------- Kernel 1: pool maxes, LDS-staged, inline cvt ----------------
// grid (32, 16): 128 i rows per block (4 waves x 32), 64-pool-row chunk (2 tiles).
__global__ __launch_bounds__(256) void k_poolmax(
    const float* __restrict__ f, const float* __restrict__ spr,
    const float* __restrict__ pag, const float* __restrict__ psp,
    u32* __restrict__ RfK, u32* __restrict__ RsK) {
    __shared__ u16 stile[BUFU];

    int tid = threadIdx.x;
    int lane = tid & 63, w = tid >> 6;
    int half = lane >> 5, li = lane & 31;
    int i = blockIdx.x * 128 + w * 32 + li;
    int pbase = blockIdx.y * 64;
    int r0 = tid >> 4, c16 = tid & 15;

    bf16x8 brf[8], brs[8];
#pragma unroll
    for (int kc = 0; kc < 8; ++kc) {
        int koff = kc * 16 + half * 8;
        brf[kc] = ldfrag(f, i, koff);
        brs[kc] = ldfrag(spr, i, koff);
    }

    f32x4 pa[2][2][2];
    ld_tile(pa, pag, psp, pbase, r0, c16);

    float rmf = -1e30f, rms = -1e30f;
#pragma unroll
    for (int jt = 0; jt < 2; ++jt) {
        __syncthreads();
        st_tile(stile, pa, r0, c16);
        __syncthreads();
        if (jt == 0) ld_tile(pa, pag, psp, pbase + 32, r0, c16);
        f32x16 accf = {}; f32x16 accs = {};
#pragma unroll
        for (int kc = 0; kc < 8; ++kc) {
            const u16* ab = stile + li * TSTRIDE + kc * 16 + half * 8;
            bf16x8 a0 = *(const bf16x8*)ab;
            bf16x8 a1 = *(const bf16x8*)(ab + TMAT);
            accf = __builtin_amdgcn_mfma_f32_32x32x16_bf16(a0, brf[kc], accf, 0, 0, 0);
            accs = __builtin_amdgcn_mfma_f32_32x32x16_bf16(a1, brs[kc], accs, 0, 0, 0);
        }
#pragma unroll
        for (int r = 0; r < 16; ++r) {
            rmf = fmaxf(rmf, accf[r]);
            rms = fmaxf(rms, accs[r]);
        }
    }
    rmf = fmaxf(rmf, __shfl_xor(rmf, 32, 64));
    rms = fmaxf(rms, __shfl_xor(rms, 32, 64));
    if (half == 0) {
        atomicMax(RfK + i, fkey(rmf));
        atomicMax(RsK + i, fkey(rms));
    }
}

// ---------------- Kernel 2: main fused two-pass kernel, double-buffered LDS ----------------
// grid (32, 32): 128 i per block (4 waves x 32), 128-j chunk (4 tiles x 32 j, visited twice).
// jt 0-3: f,s_pr -> mask bits (4b/pair) in 4 u64 regs.  jt 4-7: z,zmix -> stats.
// ONE barrier per tile: compute reads buf[jt&1] while staging writes buf[(jt+1)&1].
__global__ __launch_bounds__(256) void k_main(
    const float* __restrict__ zp, const float* __restrict__ sp,
    const float* __restrict__ fp, const float* __restrict__ xp,
    const float* __restrict__ mnb,
    const u32* __restrict__ RfK, const u32* __restrict__ RsK,
    float* __restrict__ P /* [32][6][4096] */) {
    __shared__ u16 stile[2 * BUFU];   // 34816 B

    int tid = threadIdx.x;
    int lane = tid & 63, w = tid >> 6;
    int half = lane >> 5, li = lane & 31;
    int i = blockIdx.x * 128 + w * 32 + li;
    int cbase = blockIdx.y * 128;
    int r0 = tid >> 4, c16 = tid & 15;

    bf16x8 bres0[8], bres1[8];
#pragma unroll
    for (int kc = 0; kc < 8; ++kc) {
        int koff = kc * 16 + half * 8;
        bres0[kc] = ldfrag(fp, i, koff);
        bres1[kc] = ldfrag(sp, i, koff);
    }

    float rfi = keyf(RfK[i]), rsi = keyf(RsK[i]);
    const float* mrow = mnb + (size_t)(i & 255) * 4096;
    float wsum = 0.f, ones = 0.f, Az = 0.f, Ax = 0.f, Zz = 0.f, Zx = 0.f;
    const float c1 = TEMP_INV * LOG2E;
    u64 bitsv[4];

    f32x4 pa[2][2][2];
    ld_tile(pa, fp, sp, cbase, r0, c16);
    st_tile(stile, pa, r0, c16);   // buffer 0
    __syncthreads();

#pragma unroll
    for (int jt = 0; jt < 8; ++jt) {
        int j0 = cbase + (jt & 3) * 32;
        u16* bufC = stile + (jt & 1) * BUFU;        // compute buffer
        u16* bufW = stile + ((jt + 1) & 1) * BUFU;  // write buffer (next tile)

        if (jt < 7) {   // issue next-tile loads early
            const float* n0 = (jt + 1 < 4) ? fp : zp;
            const float* n1 = (jt + 1 < 4) ? sp : xp;
            ld_tile(pa, n0, n1, cbase + ((jt + 1) & 3) * 32, r0, c16);
        }

        if (jt < 4) {
            // ---- pass 0: mask sims ----
            f32x16 accF = {}; f32x16 accS = {};
#pragma unroll
            for (int kc = 0; kc < 8; ++kc) {
                const u16* ab = bufC + li * TSTRIDE + kc * 16 + half * 8;
                bf16x8 a0 = *(const bf16x8*)ab;
                bf16x8 a1 = *(const bf16x8*)(ab + TMAT);
                accF = __builtin_amdgcn_mfma_f32_32x32x16_bf16(a0, bres0[kc], accF, 0, 0, 0);
                accS = __builtin_amdgcn_mfma_f32_32x32x16_bf16(a1, bres1[kc], accS, 0, 0, 0);
            }
            // elem r: j = j0 + (r&3) + 8*(r>>2) + 4*half  (m74/m101 C/D layout)
            u64 bits = 0;
#pragma unroll
            for (int q = 0; q < 4; ++q) {
                int jb = j0 + q * 8 + half * 4;
                uint4 kf4 = *(const uint4*)(RfK + jb);
                uint4 ks4 = *(const uint4*)(RsK + jb);
                f32x4 mb4 = *(const f32x4*)(mrow + jb);
#pragma unroll
                for (int t = 0; t < 4; ++t) {
                    int r = q * 4 + t;
                    int j = jb + t;
                    bool nm = (j != i);
                    float rfj = keyf(((const u32*)&kf4)[t]);
                    float rsj = keyf(((const u32*)&ks4)[t]);
                    bool mob = accF[r] > fminf(rfi, rfj);
                    bool meb = accS[r] > fminf(rsi, rsj);
                    bool mnbv = mb4[t] > 0.0f;
                    u32 e = ((mob && nm) ? 1u : 0u) | ((meb && nm) ? 2u : 0u) |
                            (((mob || mnbv) && nm) ? 4u : 0u);
                    bits |= (u64)e << (4 * r);
                }
            }
            bitsv[jt] = bits;
            if (jt == 3) {   // swap residents to z,zmix for pass 1
#pragma unroll
                for (int kc = 0; kc < 8; ++kc) {
                    int koff = kc * 16 + half * 8;
                    bres0[kc] = ldfrag(zp, i, koff);
                    bres1[kc] = ldfrag(xp, i, koff);
                }
            }
        } else {
            // ---- pass 1: log-prob sims + consume masks ----
            f32x16 accZ = {}; f32x16 accX = {};
#pragma unroll
            for (int kc = 0; kc < 8; ++kc) {
                const u16* ab = bufC + li * TSTRIDE + kc * 16 + half * 8;
                bf16x8 a0 = *(const bf16x8*)ab;
                bf16x8 a1 = *(const bf16x8*)(ab + TMAT);
                accZ = __builtin_amdgcn_mfma_f32_32x32x16_bf16(a0, bres0[kc], accZ, 0, 0, 0);
                accX = __builtin_amdgcn_mfma_f32_32x32x16_bf16(a1, bres1[kc], accX, 0, 0, 0);
            }
            u64 bits = bitsv[jt & 3];
#pragma unroll
            for (int r = 0; r < 16; ++r) {
                u32 e = (u32)(bits >> (4 * r)) & 7u;
                float w1 = (e & 1u) ? 1.0f : 0.0f;
                float wv = w1 + ((e & 2u) ? 0.5f : 0.0f);
                float ng = (e & 4u) ? 1.0f : 0.0f;
                float lvz = accZ[r], lvx = accX[r];
                wsum += wv; ones += w1;
                Az = fmaf(wv, lvz, Az);
                Ax = fmaf(wv, lvx, Ax);
                Zz = fmaf(ng, EXP2(fmaf(lvz, c1, -c1)), Zz);
                Zx = fmaf(ng, EXP2(fmaf(lvx, c1, -c1)), Zx);
            }
        }

        if (jt < 7) st_tile(bufW, pa, r0, c16);  // other buffer: no read hazard
        __syncthreads();
    }

    // combine two lane-halves (disjoint j sets, same i); coalesced SoA partial store
    wsum += __shfl_xor(wsum, 32, 64);
    ones += __shfl_xor(ones, 32, 64);
    Az += __shfl_xor(Az, 32, 64);
    Ax += __shfl_xor(Ax, 32, 64);
    Zz += __shfl_xor(Zz, 32, 64);
    Zx += __shfl_xor(Zx, 32, 64);
    if (half == 0) {
        float* pb = P + ((size_t)blockIdx.y * 6) * 4096 + i;
        pb[0] = wsum;
        pb[4096] = ones;
        pb[2 * 4096] = Az;
        pb[3 * 4096] = Ax;
        pb[4 * 4096] = Zz;
        pb[5 * 4096] = Zx;
    }
}

// ---------------- Kernel 3: reduce 32 chunks, per-m block means, ticketed final sum ----------------
__global__ __launch_bounds__(256) void k_final(const float* __restrict__ P,
                                               float* __restrict__ accum, u32* __restrict__ ticket,
                                               u32* __restrict__ out) {
    int t = threadIdx.x;
    int i = blockIdx.x * 256 + t;
    float wsum = 0.f, ones = 0.f, Az = 0.f, Ax = 0.f, Zz = 0.f, Zx = 0.f;
#pragma unroll
    for (int c = 0; c < 32; ++c) {
        const float* pb = P + ((size_t)c * 6) * 4096 + i;
        wsum += pb[0];
        ones += pb[4096];
        Az += pb[2 * 4096];
        Ax += pb[3 * 4096];
        Zz += pb[4 * 4096];
        Zx += pb[5 * 4096];
    }
    float dw = wsum > 0.f ? wsum : 1.0f;
    float lz = Zz > 0.f ? logf(Zz) : 0.f;
    float lx = Zx > 0.f ? logf(Zx) : 0.f;
    float mlz = (TEMP_INV * Az - wsum * (TEMP_INV + lz)) / dw;
    float mlx = (TEMP_INV * Ax - wsum * (TEMP_INV + lx)) / dw;
    float si = ones > 0.f ? wsum : 0.f;
    float ci = (mlz + mlx) * si;
#pragma unroll
    for (int d = 1; d < 64; d <<= 1) {
        ci += __shfl_xor(ci, d, 64);
        si += __shfl_xor(si, d, 64);
    }
    __shared__ float rc[4], rs[4];
    int wv = t >> 6;
    if ((t & 63) == 0) { rc[wv] = ci; rs[wv] = si; }
    __syncthreads();
    if (t == 0) {
        float cs = rc[0] + rc[1] + rc[2] + rc[3];
        float ss = rs[0] + rs[1] + rs[2] + rs[3];
        float ratio = ss > 0.f ? cs / ss : 0.f;
        atomicAdd(accum, ratio);
        __threadfence();
        u32 old = atomicAdd(ticket, 1u);
        if (old == 15u) {
            float total = atomicAdd(accum, 0.0f);  // all 16 adds complete
            __hip_bfloat16 hb = __float2bfloat16(-total / 32.0f);
            u32 bits = (u32)__bfloat16_as_ushort(hb);
            out[0] = (bits << 16) | bits;  // bf16/f32 dual-interpretation hedge (passed r3/r4/r6/r7)
        }
    }
}

extern "C" void kernel_launch(void* const* d_in, const int* in_sizes, int n_in,
                              void* d_out, int out_size, void* d_ws, size_t ws_size,
                              hipStream_t stream) {
    const float* z   = (const float*)d_in[0];
    const float* spr = (const float*)d_in[1];
    const float* f   = (const float*)d_in[2];
    const float* pag = (const float*)d_in[3];
    const float* psp = (const float*)d_in[4];
    const float* zmx = (const float*)d_in[5];
    const float* mnb = (const float*)d_in[6];

    // ws: P[32][6][4096] f32 (3.14 MB) | RfK[4096] | RsK[4096] | accum | ticket
    float* P     = (float*)d_ws;
    u32* RfK     = (u32*)((char*)d_ws + (size_t)32 * 6 * 4096 * 4);
    u32* RsK     = RfK + 4096;
    float* accum = (float*)(RsK + 4096);
    u32* ticket  = (u32*)(accum + 1);

    k_init<<<1, 256, 0, stream>>>(RfK);
    k_poolmax<<<dim3(32, 16), 256, 0, stream>>>(f, spr, pag, psp, RfK, RsK);
    k_main<<<dim3(32, 32), 256, 0, stream>>>(z, spr, f, zmx, mnb, RfK, RsK, P);
    k_final<<<16, 256, 0, stream>>>(P, accum, ticket, (u32*)d_out);
}